// Round 2
// baseline (170.815 us; speedup 1.0000x reference)
//
#include <hip/hip_runtime.h>
#include <hip/hip_bf16.h>

typedef __attribute__((ext_vector_type(8))) short short8;
typedef __attribute__((ext_vector_type(4))) float f32x4;
typedef unsigned short u16;
typedef unsigned int u32;

// B=512, M=40, H=128, D=64, C=128, K' = m*128+h = 5120, 160 K-tiles of 32.
#define NB 512
#define NM 40
#define NH 128
#define ND 64
#define NC 128
#define KTOT 5120
#define NT 160
#define XKP 136   // xkT padded row: 136 shorts (68 words, odd*4 -> 2-way max)

__device__ __forceinline__ u16 f2bf_rne(float f) {
    u32 u = __float_as_uint(f);
    u32 r = u + 0x7FFFu + ((u >> 16) & 1u);
    return (u16)(r >> 16);
}
__device__ __forceinline__ float bf2f(short s) {
    return __uint_as_float(((u32)(u16)s) << 16);
}

// b_frag[j] = bf16(s * bf16(xv[j]))  -- v_perm packs 2 elements per inst
__device__ __forceinline__ short8 bmul(float s, short8 xv) {
    union { short8 s8; u32 u4[4]; } r;
#pragma unroll
    for (int j = 0; j < 4; ++j) {
        float f0 = s * bf2f(xv[2 * j]);
        float f1 = s * bf2f(xv[2 * j + 1]);
        r.u4[j] = __builtin_amdgcn_perm(__float_as_uint(f1), __float_as_uint(f0),
                                        0x07060302u);
    }
    return r.s8;
}

// ---- pre-kernel 1: W (fp32 [C][h*40+m]) -> bf16 W3 [t][c][32] where
// k' = t*32 + kk = m*128 + h.  One block per channel c: coalesced read,
// LDS permute, 16B scattered writes (1.3 MB total).
__global__ void w3_kernel(const float* __restrict__ W, u16* __restrict__ W3) {
    __shared__ u16 kbuf[KTOT];
    const int c = blockIdx.x;
    const float* src = W + (size_t)c * KTOT;
    for (int k = threadIdx.x; k < KTOT; k += 256)
        kbuf[k] = f2bf_rne(src[k]);
    __syncthreads();
    for (int n = threadIdx.x; n < KTOT / 8; n += 256) {   // n = k'/8
        union { short8 s8; u16 e[8]; } v;
#pragma unroll
        for (int j = 0; j < 8; ++j) {
            int kp = n * 8 + j;
            int h = kp & 127, m = kp >> 7;
            v.e[j] = kbuf[h * NM + m];
        }
        int t = n >> 2, kk = (n & 3) * 8;
        *(short8*)(W3 + (size_t)t * 4096 + c * 32 + kk) = v.s8;
    }
}

// ---- pre-kernel 2: transpose xk fp32 [b][128][64] -> bf16 xkT [b][64][136]
__global__ void xkt_kernel(const float* __restrict__ xk, u16* __restrict__ xkT) {
    __shared__ float lds[128 * 65];
    int b = blockIdx.x;
    const float* src = xk + (size_t)b * (NH * ND);
    for (int i = threadIdx.x; i < NH * ND; i += 256)
        lds[(i >> 6) * 65 + (i & 63)] = src[i];
    __syncthreads();
    u16* dst = xkT + (size_t)b * (ND * XKP);
    for (int o = threadIdx.x; o < ND * XKP; o += 256) {
        int d = o / XKP;
        int h = o - d * XKP;
        float v = (h < NH) ? lds[h * 65 + d] : 0.f;
        dst[o] = f2bf_rne(v);
    }
}

// ---- main: 1 block/batch, 512 threads = 8 waves. Waves 0-3 do K-tiles
// [0,80), waves 4-7 do [80,160) on the same 4 output tiles; LDS reduce.
// A comes straight from L2 (W3 is 1.3MB, resident) -> NO barrier in K-loop.
__global__ void __launch_bounds__(512, 4) cin_main(
    const float* __restrict__ x0g, const float* __restrict__ biasg,
    const u16* __restrict__ W3, const u16* __restrict__ xkTg,
    float* __restrict__ out)
{
    // smem map: [0,17408) xkT | [17408,27648) x0s | [33792,34304) bias
    // epilogue: [0,33792) reduce buffer (4 tiles x 64 rows x stride 33 f32)
    __shared__ __align__(16) char smem[34304];
    short* xkT   = (short*)smem;
    float* x0s   = (float*)(smem + 17408);
    float* bias_s= (float*)(smem + 33792);
    float* red   = (float*)smem;

    const int tid = threadIdx.x;
    const int b = blockIdx.x;
    const int w = tid >> 6, L = tid & 63;
    const int kh = w >> 2;               // K-half
    const int wq = w & 3;                // output tile id
    const int q = L >> 4, l16 = L & 15;
    const int rowbase = (wq >> 1) << 6;  // tile: 64 rows x 32 cols
    const int colbase = (wq & 1) << 5;
    const int dcol0 = colbase + l16, dcol1 = dcol0 + 16;

    // prologue staging
    {
        const u32* src = (const u32*)(xkTg + (size_t)b * (ND * XKP));
        u32* dst = (u32*)xkT;
        for (int i = tid; i < (ND * XKP) / 2; i += 512) dst[i] = src[i];
        const float* xp = x0g + (size_t)b * (NM * ND);
        for (int i = tid; i < NM * ND; i += 512) x0s[i] = xp[i];
        if (tid < NC) bias_s[tid] = biasg[tid];
    }
    __syncthreads();

    const u16* Ap = W3 + (size_t)(rowbase + l16) * 32 + q * 8;
    auto loadA = [&](int t, short8* a) {
#pragma unroll
        for (int mt = 0; mt < 4; ++mt)
            a[mt] = *(const short8*)(Ap + (size_t)t * 4096 + mt * (16 * 32));
    };

    const int t0 = kh * 80;
    f32x4 acc[4][2] = {};
    short8 aC[4], aN[4];
    float x0v0 = 0.f, x0v1 = 0.f;
    loadA(t0, aC);

#pragma unroll 4
    for (int tt = 0; tt < 80; ++tt) {
        const int t = t0 + tt;
        const int tn = (tt + 1 < 80) ? (t + 1) : t0;   // harmless wrap load
        loadA(tn, aN);                                  // vmem prefetch first
        if ((t & 3) == 0) {                             // m advances per 4 tiles
            const int m = t >> 2;
            x0v0 = x0s[m * ND + dcol0];
            x0v1 = x0s[m * ND + dcol1];
        }
        const int hh = ((t & 3) << 5) + q * 8;
        short8 xv0 = *(const short8*)&xkT[dcol0 * XKP + hh];
        short8 xv1 = *(const short8*)&xkT[dcol1 * XKP + hh];
        short8 bf0 = bmul(x0v0, xv0);
        short8 bf1 = bmul(x0v1, xv1);
#pragma unroll
        for (int mt = 0; mt < 4; ++mt) {
            acc[mt][0] = __builtin_amdgcn_mfma_f32_16x16x32_bf16(aC[mt], bf0, acc[mt][0], 0, 0, 0);
            acc[mt][1] = __builtin_amdgcn_mfma_f32_16x16x32_bf16(aC[mt], bf1, acc[mt][1], 0, 0, 0);
        }
#pragma unroll
        for (int mt = 0; mt < 4; ++mt) aC[mt] = aN[mt];
    }

    // epilogue: C/D layout col = lane&15, row = quad*4 + reg
    __syncthreads();                       // everyone done with xkT/x0s
    if (kh == 1) {
        float* r0 = red + wq * 2112;       // 64 rows, stride 33
#pragma unroll
        for (int mt = 0; mt < 4; ++mt)
#pragma unroll
            for (int r = 0; r < 4; ++r) {
                int row = mt * 16 + q * 4 + r;
                r0[row * 33 + l16]      = acc[mt][0][r];
                r0[row * 33 + 16 + l16] = acc[mt][1][r];
            }
    }
    __syncthreads();
    if (kh == 0) {
        const float* r0 = red + wq * 2112;
        float* op = out + (size_t)b * (NC * ND);
#pragma unroll
        for (int mt = 0; mt < 4; ++mt)
#pragma unroll
            for (int r = 0; r < 4; ++r) {
                int row = mt * 16 + q * 4 + r;
                int c = rowbase + row;
                float bv = bias_s[c];
                op[c * ND + dcol0] = acc[mt][0][r] + r0[row * 33 + l16]      + bv;
                op[c * ND + dcol1] = acc[mt][1][r] + r0[row * 33 + 16 + l16] + bv;
            }
    }
}

extern "C" void kernel_launch(void* const* d_in, const int* in_sizes, int n_in,
                              void* d_out, int out_size, void* d_ws, size_t ws_size,
                              hipStream_t stream) {
    const float* x0 = (const float*)d_in[0];
    const float* xk = (const float*)d_in[1];
    const float* W  = (const float*)d_in[2];
    const float* bi = (const float*)d_in[3];
    float* out = (float*)d_out;

    u16* W3  = (u16*)d_ws;                       // 655360 shorts = 1.31 MB
    u16* xkT = (u16*)d_ws + 655360;              // 512*8704 shorts = 8.9 MB

    w3_kernel<<<NC, 256, 0, stream>>>(W, W3);
    xkt_kernel<<<NB, 256, 0, stream>>>(xk, xkT);
    cin_main<<<NB, 512, 0, stream>>>(x0, bi, W3, xkT, out);
}

// Round 3
// 125.100 us; speedup vs baseline: 1.3654x; 1.3654x over previous
//
#include <hip/hip_runtime.h>
#include <hip/hip_bf16.h>

typedef __attribute__((ext_vector_type(8))) short short8;
typedef __attribute__((ext_vector_type(4))) float f32x4;
typedef unsigned short u16;
typedef unsigned int u32;

// B=512, M=40, H=128, D=64, C=128. K' = hh*320 + m*8 + hl (h = hh*8+hl),
// 160 K-tiles of 32; tile t covers hh = t/10, m = 4*(t%10)+quad, hl = j.
#define NB 512
#define NM 40
#define NH 128
#define ND 64
#define NC 128
#define KTOT 5120
#define XKP 136   // xkT row pad: 272 B -> 2-way max on b128 reads
#define X0P 72    // x0s row pad: quad offsets 8q banks -> 2-way on b32 reads

__device__ __forceinline__ u16 f2bf_rne(float f) {
    u32 u = __float_as_uint(f);
    u32 r = u + 0x7FFFu + ((u >> 16) & 1u);
    return (u16)(r >> 16);
}
__device__ __forceinline__ float bf2f(short s) {
    return __uint_as_float(((u32)(u16)s) << 16);
}

// b_frag[j] = bf16(s * bf16(xv[j]))  -- v_perm packs 2 per inst
__device__ __forceinline__ short8 bmul(float s, short8 xv) {
    union { short8 s8; u32 u4[4]; } r;
#pragma unroll
    for (int j = 0; j < 4; ++j) {
        float f0 = s * bf2f(xv[2 * j]);
        float f1 = s * bf2f(xv[2 * j + 1]);
        r.u4[j] = __builtin_amdgcn_perm(__float_as_uint(f1), __float_as_uint(f0),
                                        0x07060302u);
    }
    return r.s8;
}

// pre-kernel: W fp32 [C][h*40+m] -> bf16 W3 [t][q][c][8], k'=t*32+q*8+j,
// n8 = t*4+q: m = n8%40, hh = n8/40, h = hh*8+j. One block per channel.
__global__ void w3_kernel(const float* __restrict__ W, u16* __restrict__ W3) {
    __shared__ u16 kbuf[KTOT];
    const int c = blockIdx.x;
    const float* src = W + (size_t)c * KTOT;
    for (int k = threadIdx.x; k < KTOT; k += 256)
        kbuf[k] = f2bf_rne(src[k]);
    __syncthreads();
    for (int n8 = threadIdx.x; n8 < 640; n8 += 256) {
        int m = n8 % 40, hh = n8 / 40;
        union { short8 s8; u16 e[8]; } v;
#pragma unroll
        for (int j = 0; j < 8; ++j)
            v.e[j] = kbuf[hh * 320 + j * 40 + m];
        int t = n8 >> 2, q = n8 & 3;
        *(short8*)(W3 + (size_t)t * 4096 + q * 1024 + c * 8) = v.s8;
    }
}

// main: 1 block/batch, 256 thr = 4 waves: (kh = K-half) x (rh = row-half).
// Wave tile 64 rows x 64 cols, 16 MFMA/iter. A staged to LDS (dbuf, 1 barrier
// per iter); B built from registers (xv reloaded per 10 iters) + 1 b32/col.
__global__ void __launch_bounds__(256) cin_main(
    const float* __restrict__ x0g, const float* __restrict__ xkg,
    const float* __restrict__ biasg, const u16* __restrict__ W3,
    float* __restrict__ out)
{
    __shared__ __align__(16) char smem[62208];
    short* A2     = (short*)smem;             // [buf][half][4096] = 32768 B
    short* xkT    = (short*)(smem + 32768);   // [64][136] bf16 = 17408 B
    float* x0s    = (float*)(smem + 50176);   // [40][72] f32 = 11520 B
    float* bias_s = (float*)(smem + 61696);   // 512 B
    float* red    = (float*)smem;             // epilogue reduce (2x17408 B)

    const int tid = threadIdx.x;
    const int b = blockIdx.x;
    const int w = tid >> 6, L = tid & 63;
    const int q = L >> 4, l16 = L & 15;
    const int kh = w >> 1;    // K-half: tiles [kh*80, kh*80+80)
    const int rh = w & 1;     // row half: rows [rh*64, rh*64+64)

    // ---- prologue: transpose xk -> bf16 xkT, x0 -> LDS, bias
    {
        const float* xp = xkg + (size_t)b * (NH * ND);
        for (int i = tid; i < 2048; i += 256) {        // float4 per (h, d4)
            int h = i >> 4, d4 = (i & 15) << 2;
            float4 v = *(const float4*)(xp + h * ND + d4);
            xkT[(d4 + 0) * XKP + h] = f2bf_rne(v.x);
            xkT[(d4 + 1) * XKP + h] = f2bf_rne(v.y);
            xkT[(d4 + 2) * XKP + h] = f2bf_rne(v.z);
            xkT[(d4 + 3) * XKP + h] = f2bf_rne(v.w);
        }
        const float* x0p = x0g + (size_t)b * (NM * ND);
        for (int i = tid; i < 640; i += 256) {
            int m = i >> 4, d4 = (i & 15) << 2;
            *(f32x4*)(x0s + m * X0P + d4) = *(const f32x4*)(x0p + m * ND + d4);
        }
        if (tid < NC) bias_s[tid] = biasg[tid];
    }

    // async A stage: wave stages its own K-half; chunks n = rh*4 + r
    auto stage = [&](int tt1, int bufb) {
        const int tglob = kh * 80 + tt1;
#pragma unroll
        for (int r = 0; r < 4; ++r) {
            const int n = rh * 4 + r;
            const u16* g = W3 + (size_t)tglob * 4096 + n * 512 + L * 8;
            short* dst = A2 + bufb * 8192 + kh * 4096 + n * 512;
            __builtin_amdgcn_global_load_lds(
                (const __attribute__((address_space(1))) void*)g,
                (__attribute__((address_space(3))) void*)dst, 16, 0, 0);
        }
    };

    stage(0, 0);

    f32x4 acc[4][4] = {};   // [mt rows][n cols]
    short8 xv[4];

    for (int tp = 0; tp < 8; ++tp) {
        const int hh = kh * 8 + tp;
#pragma unroll
        for (int n = 0; n < 4; ++n)     // xv cache: 16 B/col, 10-iter lifetime
            xv[n] = *(const short8*)&xkT[(n * 16 + l16) * XKP + hh * 8];
#pragma unroll 2
        for (int ti = 0; ti < 10; ++ti) {
            const int tt = tp * 10 + ti;
            __syncthreads();                       // buf[tt&1] staged & free
            if (tt + 1 < 80) stage(tt + 1, (tt + 1) & 1);
            const short* Ab = A2 + (tt & 1) * 8192 + kh * 4096 +
                              q * 1024 + (rh * 64 + l16) * 8;
            const float* px0 = x0s + (4 * ti + q) * X0P + l16;
            short8 a0 = *(const short8*)(Ab);
            short8 a1 = *(const short8*)(Ab + 128);
            short8 a2 = *(const short8*)(Ab + 256);
            short8 a3 = *(const short8*)(Ab + 384);
#pragma unroll
            for (int n = 0; n < 4; ++n) {
                short8 bf = bmul(px0[n * 16], xv[n]);
                acc[0][n] = __builtin_amdgcn_mfma_f32_16x16x32_bf16(a0, bf, acc[0][n], 0, 0, 0);
                acc[1][n] = __builtin_amdgcn_mfma_f32_16x16x32_bf16(a1, bf, acc[1][n], 0, 0, 0);
                acc[2][n] = __builtin_amdgcn_mfma_f32_16x16x32_bf16(a2, bf, acc[2][n], 0, 0, 0);
                acc[3][n] = __builtin_amdgcn_mfma_f32_16x16x32_bf16(a3, bf, acc[3][n], 0, 0, 0);
            }
        }
    }

    // ---- epilogue: 2-way K reduce via LDS; C/D layout col=l16, row=q*4+reg
    __syncthreads();
    float* r0 = red + rh * 4352;           // 64 rows, stride 68 (2-way banks)
    if (kh == 1) {
#pragma unroll
        for (int mt = 0; mt < 4; ++mt)
#pragma unroll
            for (int rr = 0; rr < 4; ++rr) {
                int row = mt * 16 + q * 4 + rr;
                float* p = r0 + row * 68 + l16;
                p[0]  = acc[mt][0][rr];
                p[16] = acc[mt][1][rr];
                p[32] = acc[mt][2][rr];
                p[48] = acc[mt][3][rr];
            }
    }
    __syncthreads();
    if (kh == 0) {
        float* op = out + (size_t)b * (NC * ND);
#pragma unroll
        for (int mt = 0; mt < 4; ++mt)
#pragma unroll
            for (int rr = 0; rr < 4; ++rr) {
                int row = mt * 16 + q * 4 + rr;
                int c = rh * 64 + row;
                const float* p = r0 + row * 68 + l16;
                float bv = bias_s[c];
                op[c * ND + 0  + l16] = acc[mt][0][rr] + p[0]  + bv;
                op[c * ND + 16 + l16] = acc[mt][1][rr] + p[16] + bv;
                op[c * ND + 32 + l16] = acc[mt][2][rr] + p[32] + bv;
                op[c * ND + 48 + l16] = acc[mt][3][rr] + p[48] + bv;
            }
    }
}

extern "C" void kernel_launch(void* const* d_in, const int* in_sizes, int n_in,
                              void* d_out, int out_size, void* d_ws, size_t ws_size,
                              hipStream_t stream) {
    const float* x0 = (const float*)d_in[0];
    const float* xk = (const float*)d_in[1];
    const float* W  = (const float*)d_in[2];
    const float* bi = (const float*)d_in[3];
    float* out = (float*)d_out;

    u16* W3 = (u16*)d_ws;                      // 655360 shorts = 1.31 MB

    w3_kernel<<<NC, 256, 0, stream>>>(W, W3);
    cin_main<<<NB, 256, 0, stream>>>(x0, xk, bi, W3, out);
}

// Round 4
// 120.338 us; speedup vs baseline: 1.4195x; 1.0396x over previous
//
#include <hip/hip_runtime.h>
#include <hip/hip_bf16.h>

typedef __attribute__((ext_vector_type(8))) short short8;
typedef __attribute__((ext_vector_type(4))) float f32x4;
typedef unsigned short u16;
typedef unsigned int u32;

// B=512, M=40, H=128, D=64, C=128. K' = hh*320 + m*8 + hl (h = hh*8+hl),
// 160 K-tiles of 32; tile t: hh = t/10, m = 4*(t%10)+quad, hl = j (0..7).
#define NB 512
#define NM 40
#define NH 128
#define ND 64
#define NC 128
#define KTOT 5120
#define XKP 136   // xkT row pad: 272 B -> <=2-way banks on b128 reads
#define X0P 72    // x0s row pad: <=2-way banks on b32 reads

__device__ __forceinline__ u16 f2bf_rne(float f) {
    u32 u = __float_as_uint(f);
    u32 r = u + 0x7FFFu + ((u >> 16) & 1u);
    return (u16)(r >> 16);
}
__device__ __forceinline__ float bf2f(short s) {
    return __uint_as_float(((u32)(u16)s) << 16);
}

// b_frag[j] = bf16(s * bf16(xv[j]))  -- v_perm packs 2 per inst
__device__ __forceinline__ short8 bmul(float s, short8 xv) {
    union { short8 s8; u32 u4[4]; } r;
#pragma unroll
    for (int j = 0; j < 4; ++j) {
        float f0 = s * bf2f(xv[2 * j]);
        float f1 = s * bf2f(xv[2 * j + 1]);
        r.u4[j] = __builtin_amdgcn_perm(__float_as_uint(f1), __float_as_uint(f0),
                                        0x07060302u);
    }
    return r.s8;
}

// pre-kernel: W fp32 [C][h*40+m] -> bf16 W3 [t][q][c][8], k'=t*32+q*8+j;
// n8 = t*4+q: m = n8%40, hh = n8/40, h = hh*8+j. One block per channel.
__global__ void w3_kernel(const float* __restrict__ W, u16* __restrict__ W3) {
    __shared__ u16 kbuf[KTOT];
    const int c = blockIdx.x;
    const float* src = W + (size_t)c * KTOT;
    for (int k = threadIdx.x; k < KTOT; k += 256)
        kbuf[k] = f2bf_rne(src[k]);
    __syncthreads();
    for (int n8 = threadIdx.x; n8 < 640; n8 += 256) {
        int m = n8 % 40, hh = n8 / 40;
        union { short8 s8; u16 e[8]; } v;
#pragma unroll
        for (int j = 0; j < 8; ++j)
            v.e[j] = kbuf[hh * 320 + j * 40 + m];
        int t = n8 >> 2, q = n8 & 3;
        *(short8*)(W3 + (size_t)t * 4096 + q * 1024 + c * 8) = v.s8;
    }
}

// main: 1 block/batch, 256 thr = 4 waves: (kh = K-half) x (rh = row-half).
// Wave tile 64 rows x 64 cols, 16 MFMA/iter. A comes straight from L2 into
// registers (1-tile prefetch, NO barriers in the K-loop); B built in regs
// from LDS-resident xkT (reload per 10 iters) + one b32 x0 read per col.
__global__ void __launch_bounds__(256, 2) cin_main(
    const float* __restrict__ x0g, const float* __restrict__ xkg,
    const float* __restrict__ biasg, const u16* __restrict__ W3,
    float* __restrict__ out)
{
    __shared__ __align__(16) char smem[35328];
    short* xkT    = (short*)smem;              // [64][136] bf16 = 17408 B
    float* x0s    = (float*)(smem + 17408);    // [40][72] f32  = 11520 B
    float* bias_s = (float*)(smem + 34816);    // 512 B
    float* red    = (float*)smem;              // epilogue reduce 2x17408 B

    const int tid = threadIdx.x;
    const int b = blockIdx.x;
    const int w = tid >> 6, L = tid & 63;
    const int q = L >> 4, l16 = L & 15;
    const int kh = w >> 1;    // K-half: tiles [kh*80, kh*80+80)
    const int rh = w & 1;     // row half: rows [rh*64, rh*64+64)

    // A-fragment base: W3[t][q][c][8], c = rh*64 + mt*16 + l16
    const u16* Ap = W3 + q * 1024 + (size_t)(rh * 64 + l16) * 8;
    auto loadA = [&](int t, short8* a) {
#pragma unroll
        for (int mt = 0; mt < 4; ++mt)
            a[mt] = *(const short8*)(Ap + (size_t)t * 4096 + mt * 128);
    };

    short8 aC[4], aN[4];
    loadA(kh * 80, aC);       // issue before prologue: L2 latency hidden

    // ---- prologue: transpose xk -> bf16 xkT, x0 -> LDS, bias
    {
        const float* xp = xkg + (size_t)b * (NH * ND);
        for (int i = tid; i < 2048; i += 256) {        // float4 per (h, d4)
            int h = i >> 4, d4 = (i & 15) << 2;
            float4 v = *(const float4*)(xp + h * ND + d4);
            xkT[(d4 + 0) * XKP + h] = f2bf_rne(v.x);
            xkT[(d4 + 1) * XKP + h] = f2bf_rne(v.y);
            xkT[(d4 + 2) * XKP + h] = f2bf_rne(v.z);
            xkT[(d4 + 3) * XKP + h] = f2bf_rne(v.w);
        }
        const float* x0p = x0g + (size_t)b * (NM * ND);
        for (int i = tid; i < 640; i += 256) {
            int m = i >> 4, d4 = (i & 15) << 2;
            *(f32x4*)(x0s + m * X0P + d4) = *(const f32x4*)(x0p + m * ND + d4);
        }
        if (tid < NC) bias_s[tid] = biasg[tid];
    }
    __syncthreads();

    f32x4 acc[4][4] = {};   // [mt rows][n cols]
    short8 xv[4];

    for (int tp = 0; tp < 8; ++tp) {
        const int hh = kh * 8 + tp;
#pragma unroll
        for (int n = 0; n < 4; ++n)     // xv cache: 16 B/col, 10-iter lifetime
            xv[n] = *(const short8*)&xkT[(n * 16 + l16) * XKP + hh * 8];
#pragma unroll 2
        for (int ti = 0; ti < 10; ++ti) {
            const int tt = tp * 10 + ti;
            const int tn = (tt + 1 < 80) ? (kh * 80 + tt + 1) : kh * 80;
            loadA(tn, aN);                         // register prefetch, no LDS
            const float* px0 = x0s + (4 * ti + q) * X0P + l16;
#pragma unroll
            for (int n = 0; n < 4; ++n) {
                short8 bf = bmul(px0[n * 16], xv[n]);
                acc[0][n] = __builtin_amdgcn_mfma_f32_16x16x32_bf16(aC[0], bf, acc[0][n], 0, 0, 0);
                acc[1][n] = __builtin_amdgcn_mfma_f32_16x16x32_bf16(aC[1], bf, acc[1][n], 0, 0, 0);
                acc[2][n] = __builtin_amdgcn_mfma_f32_16x16x32_bf16(aC[2], bf, acc[2][n], 0, 0, 0);
                acc[3][n] = __builtin_amdgcn_mfma_f32_16x16x32_bf16(aC[3], bf, acc[3][n], 0, 0, 0);
            }
#pragma unroll
            for (int mt = 0; mt < 4; ++mt) aC[mt] = aN[mt];
        }
    }

    // ---- epilogue: 2-way K reduce via LDS; C/D layout col=l16, row=q*4+reg
    __syncthreads();
    float* r0 = red + rh * 4352;           // 64 rows, stride 68 (2-way banks)
    if (kh == 1) {
#pragma unroll
        for (int mt = 0; mt < 4; ++mt)
#pragma unroll
            for (int rr = 0; rr < 4; ++rr) {
                int row = mt * 16 + q * 4 + rr;
                float* p = r0 + row * 68 + l16;
                p[0]  = acc[mt][0][rr];
                p[16] = acc[mt][1][rr];
                p[32] = acc[mt][2][rr];
                p[48] = acc[mt][3][rr];
            }
    }
    __syncthreads();
    if (kh == 0) {
        float* op = out + (size_t)b * (NC * ND);
#pragma unroll
        for (int mt = 0; mt < 4; ++mt)
#pragma unroll
            for (int rr = 0; rr < 4; ++rr) {
                int row = mt * 16 + q * 4 + rr;
                int c = rh * 64 + row;
                const float* p = r0 + row * 68 + l16;
                float bv = bias_s[c];
                op[c * ND + 0  + l16] = acc[mt][0][rr] + p[0]  + bv;
                op[c * ND + 16 + l16] = acc[mt][1][rr] + p[16] + bv;
                op[c * ND + 32 + l16] = acc[mt][2][rr] + p[32] + bv;
                op[c * ND + 48 + l16] = acc[mt][3][rr] + p[48] + bv;
            }
    }
}

extern "C" void kernel_launch(void* const* d_in, const int* in_sizes, int n_in,
                              void* d_out, int out_size, void* d_ws, size_t ws_size,
                              hipStream_t stream) {
    const float* x0 = (const float*)d_in[0];
    const float* xk = (const float*)d_in[1];
    const float* W  = (const float*)d_in[2];
    const float* bi = (const float*)d_in[3];
    float* out = (float*)d_out;

    u16* W3 = (u16*)d_ws;                      // 655360 shorts = 1.31 MB

    w3_kernel<<<NC, 256, 0, stream>>>(W, W3);
    cin_main<<<NB, 256, 0, stream>>>(x0, xk, bi, W3, out);
}